// Round 4
// baseline (423.472 us; speedup 1.0000x reference)
//
#include <hip/hip_runtime.h>

// TransformerLayer on MI355X (gfx950), bf16 MFMA pipeline, fp32 LN/softmax/accum.
// R4: attention v3 — S^T orientation (K as A-operand), K/Q/V frags loaded
// directly from global (no LDS staging, NO barriers), wave-private P strip in
// LDS, base-2 softmax with Q prescaled by 0.125*log2(e) in the QKV epilogue.

typedef unsigned short u16;
typedef unsigned int   u32;
typedef __bf16 bf16x8 __attribute__((ext_vector_type(8)));
typedef float  f32x4  __attribute__((ext_vector_type(4)));

#define NEG_INF (-__builtin_inff())

#if __has_builtin(__builtin_amdgcn_exp2f)
#define EXP2F(x) __builtin_amdgcn_exp2f(x)
#else
#define EXP2F(x) exp2f(x)
#endif

// fp32 -> bf16 RNE (finite inputs only)
__device__ __forceinline__ u16 f2b(float f) {
  u32 u = __float_as_uint(f);
  u = (u + 0x7fffu + ((u >> 16) & 1u)) >> 16;
  return (u16)u;
}

// async global->LDS, 16B per lane. LDS dest must be wave-uniform base + lane*16.
__device__ __forceinline__ void gload16(const void* g, void* l) {
  __builtin_amdgcn_global_load_lds(
      (const __attribute__((address_space(1))) u32*)g,
      (__attribute__((address_space(3))) u32*)l, 16, 0, 0);
}

__device__ __forceinline__ bf16x8 ld16(const u16* p) { return *(const bf16x8*)p; }

// ---------------------------------------------------------------------------
// Weight transpose + fp32->bf16. in: [z][R][C] fp32 row-major.
// out element (z,c,r) at out[(z*C + c)*R + r]  (i.e. [N][K] per matrix).
__global__ __launch_bounds__(256)
void transpose_bf16_k(const float* __restrict__ in, u16* __restrict__ out,
                      int R, int C) {
  __shared__ float tile[64][65];
  int r0 = blockIdx.x * 64, c0 = blockIdx.y * 64;
  const float* ip = in + (size_t)blockIdx.z * R * C;
  u16* op = out + (size_t)blockIdx.z * C * R;
  int tr = threadIdx.x >> 6, tc = threadIdx.x & 63;
#pragma unroll
  for (int i = 0; i < 16; i++) {
    int r = i * 4 + tr;
    tile[r][tc] = ip[(size_t)(r0 + r) * C + c0 + tc];
  }
  __syncthreads();
#pragma unroll
  for (int i = 0; i < 16; i++) {
    int c = i * 4 + tr;
    op[(size_t)(c0 + c) * R + r0 + tc] = f2b(tile[tc][c]);
  }
}

// ---------------------------------------------------------------------------
// bf16 transpose for V: vin [bh][2048][64] -> vt [bh][64][2048]
__global__ __launch_bounds__(256)
void vtrans_k(const u16* __restrict__ vin, u16* __restrict__ vt) {
  __shared__ __align__(16) u16 tile[64][72];
  int s0 = blockIdx.x * 64, bh = blockIdx.y;
  const u16* ip = vin + (size_t)bh * 2048 * 64;
  u16* op = vt + (size_t)bh * 64 * 2048;
  int t = threadIdx.x;
#pragma unroll
  for (int i = 0; i < 2; i++) {
    int idx = i * 256 + t, r = idx >> 3, c = idx & 7;
    *(uint4*)&tile[r][c * 8] = *(const uint4*)(ip + (size_t)(s0 + r) * 64 + c * 8);
  }
  __syncthreads();
#pragma unroll
  for (int i = 0; i < 16; i++) {
    int d = i * 4 + (t >> 6), s = t & 63;
    op[(size_t)d * 2048 + s0 + s] = tile[s][d];
  }
}

// ---------------------------------------------------------------------------
// LayerNorm over rows of 1024. Optional second input (residual add) and
// optional fp32 output; always writes bf16 output.
__global__ __launch_bounds__(256)
void ln_k(const float* __restrict__ in, const float* __restrict__ in2,
          const float* __restrict__ w, const float* __restrict__ b,
          float* __restrict__ outf, u16* __restrict__ outb) {
  int row = blockIdx.x, t = threadIdx.x;
  const float4* ip = (const float4*)(in + (size_t)row * 1024);
  float4 x = ip[t];
  if (in2) {
    const float4* ip2 = (const float4*)(in2 + (size_t)row * 1024);
    float4 o = ip2[t];
    x.x += o.x; x.y += o.y; x.z += o.z; x.w += o.w;
  }
  float s = x.x + x.y + x.z + x.w;
  float q = x.x * x.x + x.y * x.y + x.z * x.z + x.w * x.w;
#pragma unroll
  for (int m = 32; m; m >>= 1) { s += __shfl_xor(s, m); q += __shfl_xor(q, m); }
  __shared__ float rs[4], rq[4];
  if ((t & 63) == 0) { rs[t >> 6] = s; rq[t >> 6] = q; }
  __syncthreads();
  s = rs[0] + rs[1] + rs[2] + rs[3];
  q = rq[0] + rq[1] + rq[2] + rq[3];
  float mean = s * (1.f / 1024.f);
  float var  = q * (1.f / 1024.f) - mean * mean;
  float rstd = rsqrtf(var + 1e-5f);
  float4 wv = ((const float4*)w)[t];
  float4 bv = ((const float4*)b)[t];
  float4 y;
  y.x = (x.x - mean) * rstd * wv.x + bv.x;
  y.y = (x.y - mean) * rstd * wv.y + bv.y;
  y.z = (x.z - mean) * rstd * wv.z + bv.z;
  y.w = (x.w - mean) * rstd * wv.w + bv.w;
  if (outf) ((float4*)(outf + (size_t)row * 1024))[t] = y;
  ushort4 ub;
  ub.x = f2b(y.x); ub.y = f2b(y.y); ub.z = f2b(y.z); ub.w = f2b(y.w);
  ((ushort4*)(outb + (size_t)row * 1024))[t] = ub;
}

// ---------------------------------------------------------------------------
// 128x128 tile bf16 GEMM v2, BK=64, 256 threads (4 waves, 2x2 of 64x64 each).
// XOR chunk swizzle -> conflict-free ds_read_b128. blockIdx.z = split-K slice.
#define EPI_QKV  0
#define EPI_RELU 1
#define EPI_RES  2

// 0.125 * log2(e): folds the 1/sqrt(64) score scale AND the exp->exp2
// conversion into the Q projection (attention uses exp2 directly).
#define QSCALE 0.18033688011112042f

template <int EPI>
__global__ __launch_bounds__(256)
void gemm_k(const u16* __restrict__ A, const u16* __restrict__ Bt,
            int K, int lda, int ldbt,
            const float* __restrict__ bias0, const float* __restrict__ bias1,
            const float* __restrict__ bias2, const float* __restrict__ res,
            int ldout, u16* __restrict__ outb, float* __restrict__ outf,
            float* __restrict__ outp) {
  __shared__ __align__(16) u16 As[128 * 64];
  __shared__ __align__(16) u16 Bs[128 * 64];
  int t = threadIdx.x;
  int wave = t >> 6, lane = t & 63, quad = lane >> 4, l16 = lane & 15;
  int x7 = l16 & 7;
  int wm = (wave >> 1) * 64, wn = (wave & 1) * 64;
  int bm = blockIdx.x * 128, bn = blockIdx.y * 128;
  int zoff = blockIdx.z * K;

  const u16* Agl[4];
  const u16* Bgl[4];
#pragma unroll
  for (int i = 0; i < 4; i++) {
    int idx = i * 256 + t, r = idx >> 3, c = (idx & 7) ^ (r & 7);
    Agl[i] = A + (size_t)(bm + r) * lda + zoff + c * 8;
    Bgl[i] = Bt + (size_t)(bn + r) * ldbt + zoff + c * 8;
  }
  u16* Asl = As + t * 8;
  u16* Bsl = Bs + t * 8;

  f32x4 acc[4][4] = {};

  for (int k0 = 0; k0 < K; k0 += 64) {
#pragma unroll
    for (int i = 0; i < 4; i++) {
      gload16(Agl[i] + k0, Asl + i * 2048);
      gload16(Bgl[i] + k0, Bsl + i * 2048);
    }
    __syncthreads();
#pragma unroll
    for (int kc = 0; kc < 2; kc++) {
      bf16x8 af[4], bfr[4];
#pragma unroll
      for (int i = 0; i < 4; i++) {
        int r = wm + i * 16 + l16;
        af[i] = *(const bf16x8*)(As + r * 64 + (((kc * 4 + quad) ^ x7) * 8));
      }
#pragma unroll
      for (int j = 0; j < 4; j++) {
        int r = wn + j * 16 + l16;
        bfr[j] = *(const bf16x8*)(Bs + r * 64 + (((kc * 4 + quad) ^ x7) * 8));
      }
#pragma unroll
      for (int i = 0; i < 4; i++)
#pragma unroll
        for (int j = 0; j < 4; j++)
          acc[i][j] = __builtin_amdgcn_mfma_f32_16x16x32_bf16(af[i], bfr[j],
                                                              acc[i][j], 0, 0, 0);
    }
    __syncthreads();
  }

#pragma unroll
  for (int i = 0; i < 4; i++) {
#pragma unroll
    for (int j = 0; j < 4; j++) {
      int c = bn + wn + j * 16 + l16;
#pragma unroll
      for (int rr = 0; rr < 4; rr++) {
        int r = bm + wm + i * 16 + quad * 4 + rr;
        float v = acc[i][j][rr];
        if (EPI == EPI_QKV) {
          int which = c >> 10, h = (c >> 6) & 15, d = c & 63;
          const float* bp = which == 0 ? bias0 : (which == 1 ? bias1 : bias2);
          v += bp[h * 64 + d];
          if (which == 0) v *= QSCALE;  // prescale Q for base-2 softmax
          int bb = r >> 11, ss = r & 2047;
          outb[((size_t)(which * 32 + bb * 16 + h) * 2048 + ss) * 64 + d] = f2b(v);
        } else if (EPI == EPI_RELU) {
          v += bias0[c];
          v = v > 0.f ? v : 0.f;
          outb[(size_t)r * ldout + c] = f2b(v);
        } else {
          if (blockIdx.z == 0) {
            v += bias0[c] + res[(size_t)r * ldout + c];
            outf[(size_t)r * ldout + c] = v;
          } else {
            outp[(size_t)r * ldout + c] = v;
          }
        }
      }
    }
  }
}

// out[i] += part[i]  (fp32, float4)
__global__ __launch_bounds__(256)
void reduce_k(float* __restrict__ out, const float* __restrict__ part) {
  int i = blockIdx.x * 256 + threadIdx.x;
  float4 a = ((const float4*)part)[i];
  float4 b = ((float4*)out)[i];
  b.x += a.x; b.y += a.y; b.z += a.z; b.w += a.w;
  ((float4*)out)[i] = b;
}

// ---------------------------------------------------------------------------
// Flash attention v3, causal. Grid (32, 32), 256 threads (4 waves).
// Each wave owns 16 q-rows, loops over kv tiles independently (NO barriers).
// S^T = K·Q^T: first MFMA operand = K rows (m=kv), second = Q rows (n=q);
// C-layout gives lane(quad,l16) -> S[q=l16][kv=16g+4quad+rr], so softmax rows
// are per-l16 (2 shfl_xor reductions). P goes through a wave-private 2KB LDS
// strip (XOR-swizzled b64 writes / b128 reads) into A-operand layout.
// O = P·V uses V^T rows (= vt natural rows) as second operand.
// Q was prescaled by 0.125*log2(e) in the QKV epilogue -> softmax in base 2.
__global__ __launch_bounds__(256)
void attn_k(const u16* __restrict__ qkv, const u16* __restrict__ vt,
            float* __restrict__ o) {
  int bh = blockIdx.y, b = bh >> 4, h = bh & 15;
  int xt = b ? (31 - (int)blockIdx.x) : (int)blockIdx.x;  // causal balance
  int t = threadIdx.x;
  int wave = t >> 6, lane = t & 63, quad = lane >> 4, l16 = lane & 15;
  int x7 = l16 & 7;
  int q0 = xt * 64 + wave * 16;

  const u16* qg = qkv + (size_t)bh * (2048 * 64);
  const u16* kg = qkv + (size_t)(32 + bh) * (2048 * 64);
  const u16* vg = vt + (size_t)bh * (64 * 2048);  // [dh][s]

  __shared__ __align__(16) u16 Ps[4][16 * 64];
  u16* Pw = Ps[wave];

  // persistent Q frags (B-operand: lane l16 <-> q row q0+l16, k = dh)
  bf16x8 qf0 = ld16(qg + (size_t)(q0 + l16) * 64 + quad * 8);
  bf16x8 qf1 = ld16(qg + (size_t)(q0 + l16) * 64 + 32 + quad * 8);

  f32x4 oacc[4] = {};
  float mo = NEG_INF, ll = 0.f;
  int kmax = (q0 + 15) >> 6;

  for (int kt = 0; kt <= kmax; kt++) {
    const u16* kb = kg + (size_t)kt * 64 * 64;
    const u16* vb = vg + (size_t)kt * 64;

    // ---- S^T: per g-tile, m=kv rows g*16..+15, n = q rows ----
    f32x4 sc[4];
#pragma unroll
    for (int g = 0; g < 4; g++) {
      bf16x8 kf0 = ld16(kb + (size_t)(g * 16 + l16) * 64 + quad * 8);
      bf16x8 kf1 = ld16(kb + (size_t)(g * 16 + l16) * 64 + 32 + quad * 8);
      f32x4 s = {};
      s = __builtin_amdgcn_mfma_f32_16x16x32_bf16(kf0, qf0, s, 0, 0, 0);
      s = __builtin_amdgcn_mfma_f32_16x16x32_bf16(kf1, qf1, s, 0, 0, 0);
      sc[g] = s;
    }

    if (kt == kmax) {  // single diagonal tile per wave
#pragma unroll
      for (int g = 0; g < 4; g++) {
        int kvb = kt * 64 + g * 16 + quad * 4;
#pragma unroll
        for (int rr = 0; rr < 4; rr++)
          if (kvb + rr > q0 + l16) sc[g][rr] = NEG_INF;
      }
    }

    // ---- online softmax, row = l16 (spread across quads) ----
    float mx = sc[0][0];
#pragma unroll
    for (int g = 0; g < 4; g++)
#pragma unroll
      for (int rr = 0; rr < 4; rr++) mx = fmaxf(mx, sc[g][rr]);
    mx = fmaxf(mx, __shfl_xor(mx, 16));
    mx = fmaxf(mx, __shfl_xor(mx, 32));
    float mnew = fmaxf(mo, mx);
    float al = EXP2F(mo - mnew);
    mo = mnew;

    float sum = 0.f;
#pragma unroll
    for (int g = 0; g < 4; g++) {
      float p0 = EXP2F(sc[g][0] - mnew);
      float p1 = EXP2F(sc[g][1] - mnew);
      float p2 = EXP2F(sc[g][2] - mnew);
      float p3 = EXP2F(sc[g][3] - mnew);
      sum += (p0 + p1) + (p2 + p3);
      // truncate-pack 4 bf16 (kv = 16g+4quad .. +3) -> one ds_write_b64
      u32 lo = (__float_as_uint(p0) >> 16) | (__float_as_uint(p1) & 0xFFFF0000u);
      u32 hi = (__float_as_uint(p2) >> 16) | (__float_as_uint(p3) & 0xFFFF0000u);
      int slot = (2 * g + (quad >> 1)) ^ x7;
      *(uint2*)(Pw + l16 * 64 + slot * 8 + (quad & 1) * 4) = make_uint2(lo, hi);
    }
    sum += __shfl_xor(sum, 16);
    sum += __shfl_xor(sum, 32);
    ll = ll * al + sum;

    // rescale O: redistribute alpha from n-layout (l16) to m-layout (quad*4+rr)
#pragma unroll
    for (int rr = 0; rr < 4; rr++) {
      float ar = __shfl(al, quad * 20 + rr);
#pragma unroll
      for (int g = 0; g < 4; g++) oacc[g][rr] *= ar;
    }

    // ---- O += P·V ----
    bf16x8 pf0 = *(const bf16x8*)(Pw + l16 * 64 + ((quad ^ x7) * 8));
    bf16x8 pf1 = *(const bf16x8*)(Pw + l16 * 64 + (((4 + quad) ^ x7) * 8));
#pragma unroll
    for (int g = 0; g < 4; g++) {
      bf16x8 vf0 = ld16(vb + (size_t)(g * 16 + l16) * 2048 + quad * 8);
      bf16x8 vf1 = ld16(vb + (size_t)(g * 16 + l16) * 2048 + 32 + quad * 8);
      oacc[g] = __builtin_amdgcn_mfma_f32_16x16x32_bf16(pf0, vf0, oacc[g], 0, 0, 0);
      oacc[g] = __builtin_amdgcn_mfma_f32_16x16x32_bf16(pf1, vf1, oacc[g], 0, 0, 0);
    }
  }

  // epilogue: O row rr lives at m=quad*4+rr; l lives per-l16 -> redistribute
  float rinv[4];
#pragma unroll
  for (int rr = 0; rr < 4; rr++) rinv[rr] = 1.f / __shfl(ll, quad * 20 + rr);
  float* op = o + ((size_t)b * 2048 + q0) * 1024 + h * 64;
#pragma unroll
  for (int g = 0; g < 4; g++)
#pragma unroll
    for (int rr = 0; rr < 4; rr++)
      op[(size_t)(quad * 4 + rr) * 1024 + g * 16 + l16] = oacc[g][rr] * rinv[rr];
}

// ---------------------------------------------------------------------------
extern "C" void kernel_launch(void* const* d_in, const int* in_sizes, int n_in,
                              void* d_out, int out_size, void* d_ws, size_t ws_size,
                              hipStream_t stream) {
  const float* emb  = (const float*)d_in[0];
  const float* Wq   = (const float*)d_in[1];
  const float* bq   = (const float*)d_in[2];
  const float* Wk   = (const float*)d_in[3];
  const float* bk   = (const float*)d_in[4];
  const float* Wv   = (const float*)d_in[5];
  const float* bv   = (const float*)d_in[6];
  const float* ln1w = (const float*)d_in[7];
  const float* ln1b = (const float*)d_in[8];
  const float* ln2w = (const float*)d_in[9];
  const float* ln2b = (const float*)d_in[10];
  const float* W1   = (const float*)d_in[11];
  const float* b1   = (const float*)d_in[12];
  const float* W2   = (const float*)d_in[13];
  const float* b2   = (const float*)d_in[14];
  float* out = (float*)d_out;

  char* p = (char*)d_ws;
  u16*   Wqkv_t = (u16*)p;   p += (size_t)3072 * 1024 * 2;
  u16*   W1t    = (u16*)p;   p += (size_t)4096 * 1024 * 2;
  u16*   W2t    = (u16*)p;   p += (size_t)1024 * 4096 * 2;
  float* x      = (float*)p; p += (size_t)4096 * 1024 * 4;
  u16*   xb     = (u16*)p;   p += (size_t)4096 * 1024 * 2;
  u16*   qkvb   = (u16*)p;   p += (size_t)3 * 32 * 2048 * 64 * 2;  // 25.2 MB
  float* ob     = (float*)p; p += (size_t)4096 * 1024 * 4;         // 16.8 MB
  float* y      = (float*)p; p += (size_t)4096 * 1024 * 4;
  u16*   yb     = (u16*)p;   p += (size_t)4096 * 1024 * 2;
  u16*   hb     = (u16*)qkvb; // alias: qkvb+ob (42 MB) dead before FFN1 writes hb (33.6 MB)
  u16*   vT     = (u16*)y;    // alias: vT (8.4 MB) dead before ln2 writes y
  float* part   = x;          // alias: x (16.8 MB fp32) dead before FFN2 z=1 partial
  if (ws_size < (size_t)(p - (char*)d_ws)) return;

  transpose_bf16_k<<<dim3(16, 1, 16), 256, 0, stream>>>(Wq, Wqkv_t,                   1024, 64);
  transpose_bf16_k<<<dim3(16, 1, 16), 256, 0, stream>>>(Wk, Wqkv_t + 1024 * 1024,     1024, 64);
  transpose_bf16_k<<<dim3(16, 1, 16), 256, 0, stream>>>(Wv, Wqkv_t + 2 * 1024 * 1024, 1024, 64);
  transpose_bf16_k<<<dim3(16, 64, 1), 256, 0, stream>>>(W1, W1t, 1024, 4096);
  transpose_bf16_k<<<dim3(64, 16, 1), 256, 0, stream>>>(W2, W2t, 4096, 1024);

  ln_k<<<dim3(4096), 256, 0, stream>>>(emb, nullptr, ln1w, ln1b, x, xb);

  gemm_k<EPI_QKV><<<dim3(32, 24, 1), 256, 0, stream>>>(
      xb, Wqkv_t, 1024, 1024, 1024, bq, bk, bv, nullptr, 0, qkvb, nullptr, nullptr);

  vtrans_k<<<dim3(32, 32), 256, 0, stream>>>(qkvb + (size_t)64 * 2048 * 64, vT);

  attn_k<<<dim3(32, 32), 256, 0, stream>>>(qkvb, vT, ob);

  ln_k<<<dim3(4096), 256, 0, stream>>>(x, ob, ln2w, ln2b, y, yb);

  gemm_k<EPI_RELU><<<dim3(32, 32, 1), 256, 0, stream>>>(
      yb, W1t, 1024, 1024, 1024, b1, nullptr, nullptr, nullptr, 4096, hb, nullptr, nullptr);

  // FFN2 split-K=2: z=0 -> out (+b2+y), z=1 -> raw partial into `part`
  gemm_k<EPI_RES><<<dim3(32, 8, 2), 256, 0, stream>>>(
      hb, W2t, 2048, 4096, 4096, b2, nullptr, nullptr, y, 1024, nullptr, out, part);

  reduce_k<<<dim3(4096), 256, 0, stream>>>(out, part);
}

// Round 5
// 357.393 us; speedup vs baseline: 1.1849x; 1.1849x over previous
//
#include <hip/hip_runtime.h>

// TransformerLayer on MI355X (gfx950), bf16 MFMA pipeline, fp32 LN/softmax/accum.
// R5: attention v4 = R3 structure (8-wave blocks, LDS-staged K/V double buffer,
// 1 barrier/iter, causal pairing) + R4 math (S^T orientation -> 2-shuffle
// softmax rows, base-2 exp with prescaled Q, packed b64 P strip).

typedef unsigned short u16;
typedef unsigned int   u32;
typedef __bf16 bf16x8 __attribute__((ext_vector_type(8)));
typedef float  f32x4  __attribute__((ext_vector_type(4)));

#define NEG_INF (-__builtin_inff())

// fp32 -> bf16 RNE (finite inputs only)
__device__ __forceinline__ u16 f2b(float f) {
  u32 u = __float_as_uint(f);
  u = (u + 0x7fffu + ((u >> 16) & 1u)) >> 16;
  return (u16)u;
}

// async global->LDS, 16B per lane. LDS dest must be wave-uniform base + lane*16.
__device__ __forceinline__ void gload16(const void* g, void* l) {
  __builtin_amdgcn_global_load_lds(
      (const __attribute__((address_space(1))) u32*)g,
      (__attribute__((address_space(3))) u32*)l, 16, 0, 0);
}

__device__ __forceinline__ bf16x8 ld16(const u16* p) { return *(const bf16x8*)p; }

// ---------------------------------------------------------------------------
// Weight transpose + fp32->bf16. in: [z][R][C] fp32 row-major.
// out element (z,c,r) at out[(z*C + c)*R + r]  (i.e. [N][K] per matrix).
__global__ __launch_bounds__(256)
void transpose_bf16_k(const float* __restrict__ in, u16* __restrict__ out,
                      int R, int C) {
  __shared__ float tile[64][65];
  int r0 = blockIdx.x * 64, c0 = blockIdx.y * 64;
  const float* ip = in + (size_t)blockIdx.z * R * C;
  u16* op = out + (size_t)blockIdx.z * C * R;
  int tr = threadIdx.x >> 6, tc = threadIdx.x & 63;
#pragma unroll
  for (int i = 0; i < 16; i++) {
    int r = i * 4 + tr;
    tile[r][tc] = ip[(size_t)(r0 + r) * C + c0 + tc];
  }
  __syncthreads();
#pragma unroll
  for (int i = 0; i < 16; i++) {
    int c = i * 4 + tr;
    op[(size_t)(c0 + c) * R + r0 + tc] = f2b(tile[tc][c]);
  }
}

// ---------------------------------------------------------------------------
// bf16 transpose for V: vin [bh][2048][64] -> vt [bh][64][2048]
__global__ __launch_bounds__(256)
void vtrans_k(const u16* __restrict__ vin, u16* __restrict__ vt) {
  __shared__ __align__(16) u16 tile[64][72];
  int s0 = blockIdx.x * 64, bh = blockIdx.y;
  const u16* ip = vin + (size_t)bh * 2048 * 64;
  u16* op = vt + (size_t)bh * 64 * 2048;
  int t = threadIdx.x;
#pragma unroll
  for (int i = 0; i < 2; i++) {
    int idx = i * 256 + t, r = idx >> 3, c = idx & 7;
    *(uint4*)&tile[r][c * 8] = *(const uint4*)(ip + (size_t)(s0 + r) * 64 + c * 8);
  }
  __syncthreads();
#pragma unroll
  for (int i = 0; i < 16; i++) {
    int d = i * 4 + (t >> 6), s = t & 63;
    op[(size_t)d * 2048 + s0 + s] = tile[s][d];
  }
}

// ---------------------------------------------------------------------------
// LayerNorm over rows of 1024. Optional second input (residual add) and
// optional fp32 output; always writes bf16 output.
__global__ __launch_bounds__(256)
void ln_k(const float* __restrict__ in, const float* __restrict__ in2,
          const float* __restrict__ w, const float* __restrict__ b,
          float* __restrict__ outf, u16* __restrict__ outb) {
  int row = blockIdx.x, t = threadIdx.x;
  const float4* ip = (const float4*)(in + (size_t)row * 1024);
  float4 x = ip[t];
  if (in2) {
    const float4* ip2 = (const float4*)(in2 + (size_t)row * 1024);
    float4 o = ip2[t];
    x.x += o.x; x.y += o.y; x.z += o.z; x.w += o.w;
  }
  float s = x.x + x.y + x.z + x.w;
  float q = x.x * x.x + x.y * x.y + x.z * x.z + x.w * x.w;
#pragma unroll
  for (int m = 32; m; m >>= 1) { s += __shfl_xor(s, m); q += __shfl_xor(q, m); }
  __shared__ float rs[4], rq[4];
  if ((t & 63) == 0) { rs[t >> 6] = s; rq[t >> 6] = q; }
  __syncthreads();
  s = rs[0] + rs[1] + rs[2] + rs[3];
  q = rq[0] + rq[1] + rq[2] + rq[3];
  float mean = s * (1.f / 1024.f);
  float var  = q * (1.f / 1024.f) - mean * mean;
  float rstd = rsqrtf(var + 1e-5f);
  float4 wv = ((const float4*)w)[t];
  float4 bv = ((const float4*)b)[t];
  float4 y;
  y.x = (x.x - mean) * rstd * wv.x + bv.x;
  y.y = (x.y - mean) * rstd * wv.y + bv.y;
  y.z = (x.z - mean) * rstd * wv.z + bv.z;
  y.w = (x.w - mean) * rstd * wv.w + bv.w;
  if (outf) ((float4*)(outf + (size_t)row * 1024))[t] = y;
  ushort4 ub;
  ub.x = f2b(y.x); ub.y = f2b(y.y); ub.z = f2b(y.z); ub.w = f2b(y.w);
  ((ushort4*)(outb + (size_t)row * 1024))[t] = ub;
}

// ---------------------------------------------------------------------------
// 128x128 tile bf16 GEMM v2, BK=64, 256 threads (4 waves, 2x2 of 64x64 each).
// XOR chunk swizzle -> conflict-free ds_read_b128. blockIdx.z = split-K slice.
#define EPI_QKV  0
#define EPI_RELU 1
#define EPI_RES  2

// 0.125 * log2(e): folds the 1/sqrt(64) score scale AND the exp->exp2
// conversion into the Q projection (attention uses exp2 directly).
#define QSCALE 0.18033688011112042f

template <int EPI>
__global__ __launch_bounds__(256)
void gemm_k(const u16* __restrict__ A, const u16* __restrict__ Bt,
            int K, int lda, int ldbt,
            const float* __restrict__ bias0, const float* __restrict__ bias1,
            const float* __restrict__ bias2, const float* __restrict__ res,
            int ldout, u16* __restrict__ outb, float* __restrict__ outf,
            float* __restrict__ outp) {
  __shared__ __align__(16) u16 As[128 * 64];
  __shared__ __align__(16) u16 Bs[128 * 64];
  int t = threadIdx.x;
  int wave = t >> 6, lane = t & 63, quad = lane >> 4, l16 = lane & 15;
  int x7 = l16 & 7;
  int wm = (wave >> 1) * 64, wn = (wave & 1) * 64;
  int bm = blockIdx.x * 128, bn = blockIdx.y * 128;
  int zoff = blockIdx.z * K;

  const u16* Agl[4];
  const u16* Bgl[4];
#pragma unroll
  for (int i = 0; i < 4; i++) {
    int idx = i * 256 + t, r = idx >> 3, c = (idx & 7) ^ (r & 7);
    Agl[i] = A + (size_t)(bm + r) * lda + zoff + c * 8;
    Bgl[i] = Bt + (size_t)(bn + r) * ldbt + zoff + c * 8;
  }
  u16* Asl = As + t * 8;
  u16* Bsl = Bs + t * 8;

  f32x4 acc[4][4] = {};

  for (int k0 = 0; k0 < K; k0 += 64) {
#pragma unroll
    for (int i = 0; i < 4; i++) {
      gload16(Agl[i] + k0, Asl + i * 2048);
      gload16(Bgl[i] + k0, Bsl + i * 2048);
    }
    __syncthreads();
#pragma unroll
    for (int kc = 0; kc < 2; kc++) {
      bf16x8 af[4], bfr[4];
#pragma unroll
      for (int i = 0; i < 4; i++) {
        int r = wm + i * 16 + l16;
        af[i] = *(const bf16x8*)(As + r * 64 + (((kc * 4 + quad) ^ x7) * 8));
      }
#pragma unroll
      for (int j = 0; j < 4; j++) {
        int r = wn + j * 16 + l16;
        bfr[j] = *(const bf16x8*)(Bs + r * 64 + (((kc * 4 + quad) ^ x7) * 8));
      }
#pragma unroll
      for (int i = 0; i < 4; i++)
#pragma unroll
        for (int j = 0; j < 4; j++)
          acc[i][j] = __builtin_amdgcn_mfma_f32_16x16x32_bf16(af[i], bfr[j],
                                                              acc[i][j], 0, 0, 0);
    }
    __syncthreads();
  }

#pragma unroll
  for (int i = 0; i < 4; i++) {
#pragma unroll
    for (int j = 0; j < 4; j++) {
      int c = bn + wn + j * 16 + l16;
#pragma unroll
      for (int rr = 0; rr < 4; rr++) {
        int r = bm + wm + i * 16 + quad * 4 + rr;
        float v = acc[i][j][rr];
        if (EPI == EPI_QKV) {
          int which = c >> 10, h = (c >> 6) & 15, d = c & 63;
          const float* bp = which == 0 ? bias0 : (which == 1 ? bias1 : bias2);
          v += bp[h * 64 + d];
          if (which == 0) v *= QSCALE;  // prescale Q for base-2 softmax
          int bb = r >> 11, ss = r & 2047;
          outb[((size_t)(which * 32 + bb * 16 + h) * 2048 + ss) * 64 + d] = f2b(v);
        } else if (EPI == EPI_RELU) {
          v += bias0[c];
          v = v > 0.f ? v : 0.f;
          outb[(size_t)r * ldout + c] = f2b(v);
        } else {
          if (blockIdx.z == 0) {
            v += bias0[c] + res[(size_t)r * ldout + c];
            outf[(size_t)r * ldout + c] = v;
          } else {
            outp[(size_t)r * ldout + c] = v;
          }
        }
      }
    }
  }
}

// out[i] += part[i]  (fp32, float4)
__global__ __launch_bounds__(256)
void reduce_k(float* __restrict__ out, const float* __restrict__ part) {
  int i = blockIdx.x * 256 + threadIdx.x;
  float4 a = ((const float4*)part)[i];
  float4 b = ((float4*)out)[i];
  b.x += a.x; b.y += a.y; b.z += a.z; b.w += a.w;
  ((float4*)out)[i] = b;
}

// ---------------------------------------------------------------------------
// Flash attention v4, causal. Grid (16, 32), 512 threads (8 waves).
// Wave w owns q rows [Qt*128 + w*16, +16). K and V^T tiles (64 kv x 64, 8 KB
// each) double-buffered in LDS via gload16 (XOR chunk swizzle), 1 barrier/iter.
// S^T = K(A) x Q(B): C gives S[q=l16][kv=16g+4*quad+rr] -> softmax rows on
// l16, 2 shfl_xor reductions. Base-2 softmax (Q prescaled by 0.125*log2e).
// P packed to bf16 pairs -> 4 ds_write_b64 into wave-private 2 KB strip,
// read back as A-operand. O = P(A) x V^T(B) -> C[m=q%16][n=dh].
__global__ __launch_bounds__(512, 6)
void attn_k(const u16* __restrict__ qkv, const u16* __restrict__ vt,
            float* __restrict__ o) {
  int bh = blockIdx.y, b = bh >> 4, h = bh & 15;
  int Qt = b ? (15 - (int)blockIdx.x) : (int)blockIdx.x;  // causal balance
  int t = threadIdx.x;
  int wave = t >> 6, lane = t & 63, quad = lane >> 4, l16 = lane & 15;
  int x7 = l16 & 7;
  int q0 = Qt * 128 + wave * 16;

  const u16* qg = qkv + (size_t)bh * (2048 * 64);
  const u16* kg = qkv + (size_t)(32 + bh) * (2048 * 64);
  const u16* vg = vt + (size_t)bh * (64 * 2048);  // [dh][s]

  __shared__ __align__(16) u16 Ks[2][64 * 64];
  __shared__ __align__(16) u16 Vs[2][64 * 64];
  __shared__ __align__(16) u16 Ps[8][16 * 64];
  u16* Pw = Ps[wave];

  // staging indices: thread t -> LDS 16B slot t; global row r, chunk c^(r&7)
  int sr = t >> 3, sc_ = (t & 7) ^ (sr & 7);

  // tile 0 staging
  gload16(kg + (size_t)sr * 64 + sc_ * 8, Ks[0] + t * 8);
  gload16(vg + (size_t)sr * 2048 + sc_ * 8, Vs[0] + t * 8);

  // persistent Q frags (B-operand: n = q row = q0+l16, k = dh)
  bf16x8 qf0 = ld16(qg + (size_t)(q0 + l16) * 64 + quad * 8);
  bf16x8 qf1 = ld16(qg + (size_t)(q0 + l16) * 64 + 32 + quad * 8);

  f32x4 oacc[4] = {};
  float mo = NEG_INF, ll = 0.f;
  int kmax_w = q0 >> 6;        // wave's last (diagonal) tile
  int klast = 2 * Qt + 1;      // block's last tile (wave 7's diagonal)

  __syncthreads();

  for (int kt = 0; kt <= klast; kt++) {
    const u16* ks = Ks[kt & 1];
    const u16* vs = Vs[kt & 1];
    if (kt < klast) {  // prefetch next tile into other buffer
      gload16(kg + (size_t)((kt + 1) * 64 + sr) * 64 + sc_ * 8, Ks[(kt + 1) & 1] + t * 8);
      gload16(vg + (size_t)sr * 2048 + (kt + 1) * 64 + sc_ * 8, Vs[(kt + 1) & 1] + t * 8);
    }
    if (kt <= kmax_w) {
      // ---- S^T: A = K rows (m = kv), B = Q rows (n = q) ----
      f32x4 sc[4];
#pragma unroll
      for (int g = 0; g < 4; g++) {
        const u16* kr = ks + (g * 16 + l16) * 64;
        bf16x8 kf0 = *(const bf16x8*)(kr + ((quad ^ x7) * 8));
        bf16x8 kf1 = *(const bf16x8*)(kr + (((4 + quad) ^ x7) * 8));
        f32x4 s = {};
        s = __builtin_amdgcn_mfma_f32_16x16x32_bf16(kf0, qf0, s, 0, 0, 0);
        s = __builtin_amdgcn_mfma_f32_16x16x32_bf16(kf1, qf1, s, 0, 0, 0);
        sc[g] = s;
      }

      if (kt == kmax_w) {  // diagonal tile: mask kv > q
#pragma unroll
        for (int g = 0; g < 4; g++) {
          int kvb = kt * 64 + g * 16 + quad * 4;
#pragma unroll
          for (int rr = 0; rr < 4; rr++)
            if (kvb + rr > q0 + l16) sc[g][rr] = NEG_INF;
        }
      }

      // ---- online softmax, row = q = l16 ----
      float mx = sc[0][0];
#pragma unroll
      for (int g = 0; g < 4; g++)
#pragma unroll
        for (int rr = 0; rr < 4; rr++) mx = fmaxf(mx, sc[g][rr]);
      mx = fmaxf(mx, __shfl_xor(mx, 16));
      mx = fmaxf(mx, __shfl_xor(mx, 32));
      float mnew = fmaxf(mo, mx);
      float al = exp2f(mo - mnew);
      mo = mnew;

      float sum = 0.f;
#pragma unroll
      for (int g = 0; g < 4; g++) {
        float p0 = exp2f(sc[g][0] - mnew);
        float p1 = exp2f(sc[g][1] - mnew);
        float p2 = exp2f(sc[g][2] - mnew);
        float p3 = exp2f(sc[g][3] - mnew);
        sum += (p0 + p1) + (p2 + p3);
        // truncate-pack 4 bf16 (kv = 16g+4*quad..+3) -> one ds_write_b64
        u32 lo = (__float_as_uint(p0) >> 16) | (__float_as_uint(p1) & 0xFFFF0000u);
        u32 hi = (__float_as_uint(p2) >> 16) | (__float_as_uint(p3) & 0xFFFF0000u);
        int slot = (2 * g + (quad >> 1)) ^ x7;
        *(uint2*)(Pw + l16 * 64 + slot * 8 + (quad & 1) * 4) = make_uint2(lo, hi);
      }
      sum += __shfl_xor(sum, 16);
      sum += __shfl_xor(sum, 32);
      ll = ll * al + sum;

      // rescale O: alpha indexed by q=l16 -> redistribute to m=quad*4+rr
#pragma unroll
      for (int rr = 0; rr < 4; rr++) {
        float ar = __shfl(al, quad * 20 + rr);
#pragma unroll
        for (int g = 0; g < 4; g++) oacc[g][rr] *= ar;
      }

      // ---- O += P(A) x V^T(B) ----
      bf16x8 pf0 = *(const bf16x8*)(Pw + l16 * 64 + ((quad ^ x7) * 8));
      bf16x8 pf1 = *(const bf16x8*)(Pw + l16 * 64 + (((4 + quad) ^ x7) * 8));
#pragma unroll
      for (int g = 0; g < 4; g++) {
        const u16* vr = vs + (g * 16 + l16) * 64;
        bf16x8 vf0 = *(const bf16x8*)(vr + ((quad ^ x7) * 8));
        bf16x8 vf1 = *(const bf16x8*)(vr + (((4 + quad) ^ x7) * 8));
        oacc[g] = __builtin_amdgcn_mfma_f32_16x16x32_bf16(pf0, vf0, oacc[g], 0, 0, 0);
        oacc[g] = __builtin_amdgcn_mfma_f32_16x16x32_bf16(pf1, vf1, oacc[g], 0, 0, 0);
      }
    }
    __syncthreads();
  }

  // epilogue: O row = m = quad*4+rr, col = dh = g*16+l16; l indexed by l16
  float rinv[4];
#pragma unroll
  for (int rr = 0; rr < 4; rr++) rinv[rr] = 1.f / __shfl(ll, quad * 20 + rr);
  float* op = o + ((size_t)b * 2048 + q0) * 1024 + h * 64;
#pragma unroll
  for (int g = 0; g < 4; g++)
#pragma unroll
    for (int rr = 0; rr < 4; rr++)
      op[(size_t)(quad * 4 + rr) * 1024 + g * 16 + l16] = oacc[g][rr] * rinv[rr];
}

// ---------------------------------------------------------------------------
extern "C" void kernel_launch(void* const* d_in, const int* in_sizes, int n_in,
                              void* d_out, int out_size, void* d_ws, size_t ws_size,
                              hipStream_t stream) {
  const float* emb  = (const float*)d_in[0];
  const float* Wq   = (const float*)d_in[1];
  const float* bq   = (const float*)d_in[2];
  const float* Wk   = (const float*)d_in[3];
  const float* bk   = (const float*)d_in[4];
  const float* Wv   = (const float*)d_in[5];
  const float* bv   = (const float*)d_in[6];
  const float* ln1w = (const float*)d_in[7];
  const float* ln1b = (const float*)d_in[8];
  const float* ln2w = (const float*)d_in[9];
  const float* ln2b = (const float*)d_in[10];
  const float* W1   = (const float*)d_in[11];
  const float* b1   = (const float*)d_in[12];
  const float* W2   = (const float*)d_in[13];
  const float* b2   = (const float*)d_in[14];
  float* out = (float*)d_out;

  char* p = (char*)d_ws;
  u16*   Wqkv_t = (u16*)p;   p += (size_t)3072 * 1024 * 2;
  u16*   W1t    = (u16*)p;   p += (size_t)4096 * 1024 * 2;
  u16*   W2t    = (u16*)p;   p += (size_t)1024 * 4096 * 2;
  float* x      = (float*)p; p += (size_t)4096 * 1024 * 4;
  u16*   xb     = (u16*)p;   p += (size_t)4096 * 1024 * 2;
  u16*   qkvb   = (u16*)p;   p += (size_t)3 * 32 * 2048 * 64 * 2;  // 25.2 MB
  float* ob     = (float*)p; p += (size_t)4096 * 1024 * 4;         // 16.8 MB
  float* y      = (float*)p; p += (size_t)4096 * 1024 * 4;
  u16*   yb     = (u16*)p;   p += (size_t)4096 * 1024 * 2;
  u16*   hb     = (u16*)qkvb; // alias: qkvb+ob (42 MB) dead before FFN1 writes hb (33.6 MB)
  u16*   vT     = (u16*)y;    // alias: vT (8.4 MB) dead before ln2 writes y
  float* part   = x;          // alias: x (16.8 MB fp32) dead before FFN2 z=1 partial
  if (ws_size < (size_t)(p - (char*)d_ws)) return;

  transpose_bf16_k<<<dim3(16, 1, 16), 256, 0, stream>>>(Wq, Wqkv_t,                   1024, 64);
  transpose_bf16_k<<<dim3(16, 1, 16), 256, 0, stream>>>(Wk, Wqkv_t + 1024 * 1024,     1024, 64);
  transpose_bf16_k<<<dim3(16, 1, 16), 256, 0, stream>>>(Wv, Wqkv_t + 2 * 1024 * 1024, 1024, 64);
  transpose_bf16_k<<<dim3(16, 64, 1), 256, 0, stream>>>(W1, W1t, 1024, 4096);
  transpose_bf16_k<<<dim3(64, 16, 1), 256, 0, stream>>>(W2, W2t, 4096, 1024);

  ln_k<<<dim3(4096), 256, 0, stream>>>(emb, nullptr, ln1w, ln1b, x, xb);

  gemm_k<EPI_QKV><<<dim3(32, 24, 1), 256, 0, stream>>>(
      xb, Wqkv_t, 1024, 1024, 1024, bq, bk, bv, nullptr, 0, qkvb, nullptr, nullptr);

  vtrans_k<<<dim3(32, 32), 256, 0, stream>>>(qkvb + (size_t)64 * 2048 * 64, vT);

  attn_k<<<dim3(16, 32), 512, 0, stream>>>(qkvb, vT, ob);

  ln_k<<<dim3(4096), 256, 0, stream>>>(x, ob, ln2w, ln2b, y, yb);

  gemm_k<EPI_RELU><<<dim3(32, 32, 1), 256, 0, stream>>>(
      yb, W1t, 1024, 1024, 1024, b1, nullptr, nullptr, nullptr, 4096, hb, nullptr, nullptr);

  // FFN2 split-K=2: z=0 -> out (+b2+y), z=1 -> raw partial into `part`
  gemm_k<EPI_RES><<<dim3(32, 8, 2), 256, 0, stream>>>(
      hb, W2t, 2048, 4096, 4096, b2, nullptr, nullptr, y, 1024, nullptr, out, part);

  reduce_k<<<dim3(4096), 256, 0, stream>>>(out, part);
}

// Round 6
// 333.100 us; speedup vs baseline: 1.2713x; 1.0729x over previous
//
#include <hip/hip_runtime.h>

// TransformerLayer on MI355X (gfx950), bf16 MFMA pipeline, fp32 LN/softmax/accum.
// R6: attn VALU diet (raw v_exp_f32, v_perm P-pack, LDS-aux alpha bcast),
// launch fusion (QKV transposes merged, W1+W2 merged), named GEMM wrappers
// for profile visibility. GEMM/attn structure otherwise = R5 (verified).

typedef unsigned short u16;
typedef unsigned int   u32;
typedef __bf16 bf16x8 __attribute__((ext_vector_type(8)));
typedef float  f32x4  __attribute__((ext_vector_type(4)));

#define NEG_INF (-__builtin_inff())

#if __has_builtin(__builtin_amdgcn_exp2f)
#define EXP2F(x) __builtin_amdgcn_exp2f(x)
#else
#define EXP2F(x) exp2f(x)
#endif

// pack hi16(b)|hi16(a)<<16? -> result = lo16:=a.hi16, hi16:=b.hi16 (trunc bf16 pair)
__device__ __forceinline__ u32 pack_bf16_trunc(float a, float b) {
#if __has_builtin(__builtin_amdgcn_perm)
  return __builtin_amdgcn_perm(__float_as_uint(b), __float_as_uint(a), 0x07060302u);
#else
  return (__float_as_uint(a) >> 16) | (__float_as_uint(b) & 0xFFFF0000u);
#endif
}

// fp32 -> bf16 RNE (finite inputs only)
__device__ __forceinline__ u16 f2b(float f) {
  u32 u = __float_as_uint(f);
  u = (u + 0x7fffu + ((u >> 16) & 1u)) >> 16;
  return (u16)u;
}

// async global->LDS, 16B per lane. LDS dest must be wave-uniform base + lane*16.
__device__ __forceinline__ void gload16(const void* g, void* l) {
  __builtin_amdgcn_global_load_lds(
      (const __attribute__((address_space(1))) u32*)g,
      (__attribute__((address_space(3))) u32*)l, 16, 0, 0);
}

__device__ __forceinline__ bf16x8 ld16(const u16* p) { return *(const bf16x8*)p; }

// ---------------------------------------------------------------------------
// QKV weight transpose + fp32->bf16, all 48 head-matrices in one launch.
// Wq/Wk/Wv: [16][1024][64] fp32. out: which*1M + (sub*64 + c)*1024 + r.
__global__ __launch_bounds__(256)
void transpose_qkv_k(const float* __restrict__ Wq, const float* __restrict__ Wk,
                     const float* __restrict__ Wv, u16* __restrict__ out) {
  __shared__ float tile[64][65];
  int z = blockIdx.z, which = z >> 4, sub = z & 15;
  const float* in = which == 0 ? Wq : (which == 1 ? Wk : Wv);
  const float* ip = in + (size_t)sub * 1024 * 64;
  u16* op = out + (size_t)which * 1024 * 1024 + (size_t)sub * 64 * 1024;
  int r0 = blockIdx.x * 64;
  int tr = threadIdx.x >> 6, tc = threadIdx.x & 63;
#pragma unroll
  for (int i = 0; i < 16; i++) {
    int r = i * 4 + tr;
    tile[r][tc] = ip[(size_t)(r0 + r) * 64 + tc];
  }
  __syncthreads();
#pragma unroll
  for (int i = 0; i < 16; i++) {
    int c = i * 4 + tr;
    op[(size_t)c * 1024 + r0 + tc] = f2b(tile[tc][c]);
  }
}

// ---------------------------------------------------------------------------
// W1 (1024x4096) and W2 (4096x1024) transpose+bf16 in ONE flat-grid launch.
// out layout per matrix: [N][K] ([C][R]).
__global__ __launch_bounds__(256)
void transpose_w12_k(const float* __restrict__ W1, const float* __restrict__ W2,
                     u16* __restrict__ W1t, u16* __restrict__ W2t) {
  __shared__ float tile[64][65];
  int id = blockIdx.x;
  const float* in; u16* out; int R, C, r0, c0;
  if (id < 1024) { in = W1; out = W1t; R = 1024; C = 4096; r0 = (id & 15) * 64; c0 = (id >> 4) * 64; }
  else { id -= 1024; in = W2; out = W2t; R = 4096; C = 1024; r0 = (id >> 4) * 64; c0 = (id & 15) * 64; }
  int tr = threadIdx.x >> 6, tc = threadIdx.x & 63;
#pragma unroll
  for (int i = 0; i < 16; i++) {
    int r = i * 4 + tr;
    tile[r][tc] = in[(size_t)(r0 + r) * C + c0 + tc];
  }
  __syncthreads();
#pragma unroll
  for (int i = 0; i < 16; i++) {
    int c = i * 4 + tr;
    out[(size_t)(c0 + c) * R + r0 + tc] = f2b(tile[tc][c]);
  }
}

// ---------------------------------------------------------------------------
// bf16 transpose for V: vin [bh][2048][64] -> vt [bh][64][2048]
__global__ __launch_bounds__(256)
void vtrans_k(const u16* __restrict__ vin, u16* __restrict__ vt) {
  __shared__ __align__(16) u16 tile[64][72];
  int s0 = blockIdx.x * 64, bh = blockIdx.y;
  const u16* ip = vin + (size_t)bh * 2048 * 64;
  u16* op = vt + (size_t)bh * 64 * 2048;
  int t = threadIdx.x;
#pragma unroll
  for (int i = 0; i < 2; i++) {
    int idx = i * 256 + t, r = idx >> 3, c = idx & 7;
    *(uint4*)&tile[r][c * 8] = *(const uint4*)(ip + (size_t)(s0 + r) * 64 + c * 8);
  }
  __syncthreads();
#pragma unroll
  for (int i = 0; i < 16; i++) {
    int d = i * 4 + (t >> 6), s = t & 63;
    op[(size_t)d * 2048 + s0 + s] = tile[s][d];
  }
}

// ---------------------------------------------------------------------------
// LayerNorm over rows of 1024.
__global__ __launch_bounds__(256)
void ln_k(const float* __restrict__ in, const float* __restrict__ in2,
          const float* __restrict__ w, const float* __restrict__ b,
          float* __restrict__ outf, u16* __restrict__ outb) {
  int row = blockIdx.x, t = threadIdx.x;
  const float4* ip = (const float4*)(in + (size_t)row * 1024);
  float4 x = ip[t];
  if (in2) {
    const float4* ip2 = (const float4*)(in2 + (size_t)row * 1024);
    float4 o = ip2[t];
    x.x += o.x; x.y += o.y; x.z += o.z; x.w += o.w;
  }
  float s = x.x + x.y + x.z + x.w;
  float q = x.x * x.x + x.y * x.y + x.z * x.z + x.w * x.w;
#pragma unroll
  for (int m = 32; m; m >>= 1) { s += __shfl_xor(s, m); q += __shfl_xor(q, m); }
  __shared__ float rs[4], rq[4];
  if ((t & 63) == 0) { rs[t >> 6] = s; rq[t >> 6] = q; }
  __syncthreads();
  s = rs[0] + rs[1] + rs[2] + rs[3];
  q = rq[0] + rq[1] + rq[2] + rq[3];
  float mean = s * (1.f / 1024.f);
  float var  = q * (1.f / 1024.f) - mean * mean;
  float rstd = rsqrtf(var + 1e-5f);
  float4 wv = ((const float4*)w)[t];
  float4 bv = ((const float4*)b)[t];
  float4 y;
  y.x = (x.x - mean) * rstd * wv.x + bv.x;
  y.y = (x.y - mean) * rstd * wv.y + bv.y;
  y.z = (x.z - mean) * rstd * wv.z + bv.z;
  y.w = (x.w - mean) * rstd * wv.w + bv.w;
  if (outf) ((float4*)(outf + (size_t)row * 1024))[t] = y;
  ushort4 ub;
  ub.x = f2b(y.x); ub.y = f2b(y.y); ub.z = f2b(y.z); ub.w = f2b(y.w);
  ((ushort4*)(outb + (size_t)row * 1024))[t] = ub;
}

// ---------------------------------------------------------------------------
// 128x128 tile bf16 GEMM body, BK=64, 256 threads (4 waves, 2x2 of 64x64).
// XOR chunk swizzle -> conflict-free ds_read_b128. blockIdx.z = split-K slice.
#define EPI_QKV  0
#define EPI_RELU 1
#define EPI_RES  2

// 0.125 * log2(e): folds the 1/sqrt(64) score scale AND the exp->exp2
// conversion into the Q projection (attention uses exp2 directly).
#define QSCALE 0.18033688011112042f

template <int EPI>
__device__ __forceinline__
void gemm_body(const u16* __restrict__ A, const u16* __restrict__ Bt,
               int K, int lda, int ldbt,
               const float* __restrict__ bias0, const float* __restrict__ bias1,
               const float* __restrict__ bias2, const float* __restrict__ res,
               int ldout, u16* __restrict__ outb, float* __restrict__ outf,
               float* __restrict__ outp) {
  __shared__ __align__(16) u16 As[128 * 64];
  __shared__ __align__(16) u16 Bs[128 * 64];
  int t = threadIdx.x;
  int wave = t >> 6, lane = t & 63, quad = lane >> 4, l16 = lane & 15;
  int x7 = l16 & 7;
  int wm = (wave >> 1) * 64, wn = (wave & 1) * 64;
  int bm = blockIdx.x * 128, bn = blockIdx.y * 128;
  int zoff = blockIdx.z * K;

  const u16* Agl[4];
  const u16* Bgl[4];
#pragma unroll
  for (int i = 0; i < 4; i++) {
    int idx = i * 256 + t, r = idx >> 3, c = (idx & 7) ^ (r & 7);
    Agl[i] = A + (size_t)(bm + r) * lda + zoff + c * 8;
    Bgl[i] = Bt + (size_t)(bn + r) * ldbt + zoff + c * 8;
  }
  u16* Asl = As + t * 8;
  u16* Bsl = Bs + t * 8;

  f32x4 acc[4][4] = {};

  for (int k0 = 0; k0 < K; k0 += 64) {
#pragma unroll
    for (int i = 0; i < 4; i++) {
      gload16(Agl[i] + k0, Asl + i * 2048);
      gload16(Bgl[i] + k0, Bsl + i * 2048);
    }
    __syncthreads();
#pragma unroll
    for (int kc = 0; kc < 2; kc++) {
      bf16x8 af[4], bfr[4];
#pragma unroll
      for (int i = 0; i < 4; i++) {
        int r = wm + i * 16 + l16;
        af[i] = *(const bf16x8*)(As + r * 64 + (((kc * 4 + quad) ^ x7) * 8));
      }
#pragma unroll
      for (int j = 0; j < 4; j++) {
        int r = wn + j * 16 + l16;
        bfr[j] = *(const bf16x8*)(Bs + r * 64 + (((kc * 4 + quad) ^ x7) * 8));
      }
#pragma unroll
      for (int i = 0; i < 4; i++)
#pragma unroll
        for (int j = 0; j < 4; j++)
          acc[i][j] = __builtin_amdgcn_mfma_f32_16x16x32_bf16(af[i], bfr[j],
                                                              acc[i][j], 0, 0, 0);
    }
    __syncthreads();
  }

#pragma unroll
  for (int i = 0; i < 4; i++) {
#pragma unroll
    for (int j = 0; j < 4; j++) {
      int c = bn + wn + j * 16 + l16;
#pragma unroll
      for (int rr = 0; rr < 4; rr++) {
        int r = bm + wm + i * 16 + quad * 4 + rr;
        float v = acc[i][j][rr];
        if (EPI == EPI_QKV) {
          int which = c >> 10, h = (c >> 6) & 15, d = c & 63;
          const float* bp = which == 0 ? bias0 : (which == 1 ? bias1 : bias2);
          v += bp[h * 64 + d];
          if (which == 0) v *= QSCALE;  // prescale Q for base-2 softmax
          int bb = r >> 11, ss = r & 2047;
          outb[((size_t)(which * 32 + bb * 16 + h) * 2048 + ss) * 64 + d] = f2b(v);
        } else if (EPI == EPI_RELU) {
          v += bias0[c];
          v = v > 0.f ? v : 0.f;
          outb[(size_t)r * ldout + c] = f2b(v);
        } else {
          if (blockIdx.z == 0) {
            v += bias0[c] + res[(size_t)r * ldout + c];
            outf[(size_t)r * ldout + c] = v;
          } else {
            outp[(size_t)r * ldout + c] = v;
          }
        }
      }
    }
  }
}

__global__ __launch_bounds__(256)
void qkv_gemm(const u16* A, const u16* Bt, int K, int lda, int ldbt,
              const float* b0, const float* b1, const float* b2,
              u16* outb) {
  gemm_body<EPI_QKV>(A, Bt, K, lda, ldbt, b0, b1, b2, nullptr, 0, outb, nullptr, nullptr);
}
__global__ __launch_bounds__(256)
void ffn1_gemm(const u16* A, const u16* Bt, int K, int lda, int ldbt,
               const float* b0, int ldout, u16* outb) {
  gemm_body<EPI_RELU>(A, Bt, K, lda, ldbt, b0, nullptr, nullptr, nullptr, ldout, outb, nullptr, nullptr);
}
__global__ __launch_bounds__(256)
void ffn2_gemm(const u16* A, const u16* Bt, int K, int lda, int ldbt,
               const float* b0, const float* res, int ldout,
               float* outf, float* outp) {
  gemm_body<EPI_RES>(A, Bt, K, lda, ldbt, b0, nullptr, nullptr, res, ldout, nullptr, outf, outp);
}

// out[i] += part[i]  (fp32, float4)
__global__ __launch_bounds__(256)
void reduce_k(float* __restrict__ out, const float* __restrict__ part) {
  int i = blockIdx.x * 256 + threadIdx.x;
  float4 a = ((const float4*)part)[i];
  float4 b = ((float4*)out)[i];
  b.x += a.x; b.y += a.y; b.z += a.z; b.w += a.w;
  ((float4*)out)[i] = b;
}

// ---------------------------------------------------------------------------
// Flash attention v5, causal. Grid (16, 32), 512 threads (8 waves).
// = R5 structure (LDS-staged K/V dbuf, 1 barrier/iter, S^T orientation,
// 2-shuffle softmax rows) with raw v_exp_f32, v_perm P-pack, and alpha
// broadcast via a 64B per-wave LDS aux (no bpermutes in the rescale).
__global__ __launch_bounds__(512, 6)
void attn_k(const u16* __restrict__ qkv, const u16* __restrict__ vt,
            float* __restrict__ o) {
  int bh = blockIdx.y, b = bh >> 4, h = bh & 15;
  int Qt = b ? (15 - (int)blockIdx.x) : (int)blockIdx.x;  // causal balance
  int t = threadIdx.x;
  int wave = t >> 6, lane = t & 63, quad = lane >> 4, l16 = lane & 15;
  int x7 = l16 & 7;
  int q0 = Qt * 128 + wave * 16;

  const u16* qg = qkv + (size_t)bh * (2048 * 64);
  const u16* kg = qkv + (size_t)(32 + bh) * (2048 * 64);
  const u16* vg = vt + (size_t)bh * (64 * 2048);  // [dh][s]

  __shared__ __align__(16) u16 Ks[2][64 * 64];
  __shared__ __align__(16) u16 Vs[2][64 * 64];
  __shared__ __align__(16) u16 Ps[8][16 * 64 + 32];  // +64B aux per wave
  u16* Pw = Ps[wave];
  float* auxf = (float*)(Pw + 1024);

  int sr = t >> 3, sc_ = (t & 7) ^ (sr & 7);

  gload16(kg + (size_t)sr * 64 + sc_ * 8, Ks[0] + t * 8);
  gload16(vg + (size_t)sr * 2048 + sc_ * 8, Vs[0] + t * 8);

  bf16x8 qf0 = ld16(qg + (size_t)(q0 + l16) * 64 + quad * 8);
  bf16x8 qf1 = ld16(qg + (size_t)(q0 + l16) * 64 + 32 + quad * 8);

  f32x4 oacc[4] = {};
  float mo = NEG_INF, ll = 0.f;
  int kmax_w = q0 >> 6;
  int klast = 2 * Qt + 1;

  __syncthreads();

  for (int kt = 0; kt <= klast; kt++) {
    const u16* ks = Ks[kt & 1];
    const u16* vs = Vs[kt & 1];
    if (kt < klast) {
      gload16(kg + (size_t)((kt + 1) * 64 + sr) * 64 + sc_ * 8, Ks[(kt + 1) & 1] + t * 8);
      gload16(vg + (size_t)sr * 2048 + (kt + 1) * 64 + sc_ * 8, Vs[(kt + 1) & 1] + t * 8);
    }
    if (kt <= kmax_w) {
      // ---- S^T: A = K rows (m = kv), B = Q rows (n = q) ----
      f32x4 sc[4];
#pragma unroll
      for (int g = 0; g < 4; g++) {
        const u16* kr = ks + (g * 16 + l16) * 64;
        bf16x8 kf0 = *(const bf16x8*)(kr + ((quad ^ x7) * 8));
        bf16x8 kf1 = *(const bf16x8*)(kr + (((4 + quad) ^ x7) * 8));
        f32x4 s = {};
        s = __builtin_amdgcn_mfma_f32_16x16x32_bf16(kf0, qf0, s, 0, 0, 0);
        s = __builtin_amdgcn_mfma_f32_16x16x32_bf16(kf1, qf1, s, 0, 0, 0);
        sc[g] = s;
      }

      if (kt == kmax_w) {  // diagonal tile: mask kv > q
#pragma unroll
        for (int g = 0; g < 4; g++) {
          int kvb = kt * 64 + g * 16 + quad * 4;
#pragma unroll
          for (int rr = 0; rr < 4; rr++)
            if (kvb + rr > q0 + l16) sc[g][rr] = NEG_INF;
        }
      }

      // ---- online softmax, row = q = l16 ----
      float mx = sc[0][0];
#pragma unroll
      for (int g = 0; g < 4; g++)
#pragma unroll
        for (int rr = 0; rr < 4; rr++) mx = fmaxf(mx, sc[g][rr]);
      mx = fmaxf(mx, __shfl_xor(mx, 16));
      mx = fmaxf(mx, __shfl_xor(mx, 32));
      float mnew = fmaxf(mo, mx);
      float al = EXP2F(mo - mnew);
      mo = mnew;

      float sum = 0.f;
#pragma unroll
      for (int g = 0; g < 4; g++) {
        float p0 = EXP2F(sc[g][0] - mnew);
        float p1 = EXP2F(sc[g][1] - mnew);
        float p2 = EXP2F(sc[g][2] - mnew);
        float p3 = EXP2F(sc[g][3] - mnew);
        sum += (p0 + p1) + (p2 + p3);
        u32 lo = pack_bf16_trunc(p0, p1);
        u32 hi = pack_bf16_trunc(p2, p3);
        int slot = (2 * g + (quad >> 1)) ^ x7;
        *(uint2*)(Pw + l16 * 64 + slot * 8 + (quad & 1) * 4) = make_uint2(lo, hi);
      }
      sum += __shfl_xor(sum, 16);
      sum += __shfl_xor(sum, 32);
      ll = ll * al + sum;

      // rescale O: alpha indexed by q=l16 -> broadcast via per-wave LDS aux
      if (lane < 16) auxf[lane] = al;
      f32x4 av = *(const f32x4*)(auxf + quad * 4);
#pragma unroll
      for (int g = 0; g < 4; g++)
#pragma unroll
        for (int rr = 0; rr < 4; rr++) oacc[g][rr] *= av[rr];

      // ---- O += P(A) x V^T(B) ----
      bf16x8 pf0 = *(const bf16x8*)(Pw + l16 * 64 + ((quad ^ x7) * 8));
      bf16x8 pf1 = *(const bf16x8*)(Pw + l16 * 64 + (((4 + quad) ^ x7) * 8));
#pragma unroll
      for (int g = 0; g < 4; g++) {
        const u16* vr = vs + (g * 16 + l16) * 64;
        bf16x8 vf0 = *(const bf16x8*)(vr + ((quad ^ x7) * 8));
        bf16x8 vf1 = *(const bf16x8*)(vr + (((4 + quad) ^ x7) * 8));
        oacc[g] = __builtin_amdgcn_mfma_f32_16x16x32_bf16(pf0, vf0, oacc[g], 0, 0, 0);
        oacc[g] = __builtin_amdgcn_mfma_f32_16x16x32_bf16(pf1, vf1, oacc[g], 0, 0, 0);
      }
    }
    __syncthreads();
  }

  // epilogue: O row = m = quad*4+rr, col = dh = g*16+l16; l indexed by l16
  if (lane < 16) auxf[lane] = ll;
  f32x4 lv = *(const f32x4*)(auxf + quad * 4);
  float rinv[4];
#pragma unroll
  for (int rr = 0; rr < 4; rr++) rinv[rr] = 1.f / lv[rr];
  float* op = o + ((size_t)b * 2048 + q0) * 1024 + h * 64;
#pragma unroll
  for (int g = 0; g < 4; g++)
#pragma unroll
    for (int rr = 0; rr < 4; rr++)
      op[(size_t)(quad * 4 + rr) * 1024 + g * 16 + l16] = oacc[g][rr] * rinv[rr];
}

// ---------------------------------------------------------------------------
extern "C" void kernel_launch(void* const* d_in, const int* in_sizes, int n_in,
                              void* d_out, int out_size, void* d_ws, size_t ws_size,
                              hipStream_t stream) {
  const float* emb  = (const float*)d_in[0];
  const float* Wq   = (const float*)d_in[1];
  const float* bq   = (const float*)d_in[2];
  const float* Wk   = (const float*)d_in[3];
  const float* bk   = (const float*)d_in[4];
  const float* Wv   = (const float*)d_in[5];
  const float* bv   = (const float*)d_in[6];
  const float* ln1w = (const float*)d_in[7];
  const float* ln1b = (const float*)d_in[8];
  const float* ln2w = (const float*)d_in[9];
  const float* ln2b = (const float*)d_in[10];
  const float* W1   = (const float*)d_in[11];
  const float* b1   = (const float*)d_in[12];
  const float* W2   = (const float*)d_in[13];
  const float* b2   = (const float*)d_in[14];
  float* out = (float*)d_out;

  char* p = (char*)d_ws;
  u16*   Wqkv_t = (u16*)p;   p += (size_t)3072 * 1024 * 2;
  u16*   W1t    = (u16*)p;   p += (size_t)4096 * 1024 * 2;
  u16*   W2t    = (u16*)p;   p += (size_t)1024 * 4096 * 2;
  float* x      = (float*)p; p += (size_t)4096 * 1024 * 4;
  u16*   xb     = (u16*)p;   p += (size_t)4096 * 1024 * 2;
  u16*   qkvb   = (u16*)p;   p += (size_t)3 * 32 * 2048 * 64 * 2;  // 25.2 MB
  float* ob     = (float*)p; p += (size_t)4096 * 1024 * 4;         // 16.8 MB
  float* y      = (float*)p; p += (size_t)4096 * 1024 * 4;
  u16*   yb     = (u16*)p;   p += (size_t)4096 * 1024 * 2;
  u16*   hb     = (u16*)qkvb; // alias: qkvb+ob (42 MB) dead before FFN1 writes hb (33.6 MB)
  u16*   vT     = (u16*)y;    // alias: vT (8.4 MB) dead before ln2 writes y
  float* part   = x;          // alias: x (16.8 MB fp32) dead before FFN2 z=1 partial
  if (ws_size < (size_t)(p - (char*)d_ws)) return;

  transpose_qkv_k<<<dim3(16, 1, 48), 256, 0, stream>>>(Wq, Wk, Wv, Wqkv_t);
  transpose_w12_k<<<dim3(2048), 256, 0, stream>>>(W1, W2, W1t, W2t);

  ln_k<<<dim3(4096), 256, 0, stream>>>(emb, nullptr, ln1w, ln1b, x, xb);

  qkv_gemm<<<dim3(32, 24, 1), 256, 0, stream>>>(
      xb, Wqkv_t, 1024, 1024, 1024, bq, bk, bv, qkvb);

  vtrans_k<<<dim3(32, 32), 256, 0, stream>>>(qkvb + (size_t)64 * 2048 * 64, vT);

  attn_k<<<dim3(16, 32), 512, 0, stream>>>(qkvb, vT, ob);

  ln_k<<<dim3(4096), 256, 0, stream>>>(x, ob, ln2w, ln2b, y, yb);

  ffn1_gemm<<<dim3(32, 32, 1), 256, 0, stream>>>(
      yb, W1t, 1024, 1024, 1024, b1, 4096, hb);

  // FFN2 split-K=2: z=0 -> out (+b2+y), z=1 -> raw partial into `part`
  ffn2_gemm<<<dim3(32, 8, 2), 256, 0, stream>>>(
      hb, W2t, 2048, 4096, 4096, b2, y, 1024, out, part);

  reduce_k<<<dim3(4096), 256, 0, stream>>>(out, part);
}